// Round 22
// baseline (268.146 us; speedup 1.0000x reference)
//
#include <hip/hip_runtime.h>
#include <cstdint>
#include <cstddef>

// ---------- types ----------
using short8_t = __attribute__((ext_vector_type(8))) short;
using f32x4    = __attribute__((ext_vector_type(4))) float;
typedef unsigned short bfu16;

constexpr int   Nn   = 16;
constexpr int   Tt   = 1024;
constexpr int   IDIM = 512;
constexpr int   Vv   = 4096;
constexpr int   Ss   = 128;
constexpr int   Ll   = 2 * Ss + 1;   // 257
constexpr int   LS   = 132;          // plabT slot count (row 0 = blank used)
constexpr int   PST  = LS * Tt;      // per-sample plabT stride (floats)
constexpr int   PKS  = Tt * 128;     // per-sample pkP stride (floats)
constexpr float NEGV = -1e30f;
constexpr float L2E  = 1.4426950408889634f;  // log2(e)
constexpr float LN2  = 0.6931471805599453f;  // ln(2)

// ---------- helpers ----------
__device__ __forceinline__ float fexp2(float x) { return __builtin_amdgcn_exp2f(x); }
__device__ __forceinline__ float flog2(float x) { return __builtin_amdgcn_logf(x); }

// DPP wave_shr:1 lane shift (lane i <- lane i-1), lane 0 -> 0 (bound_ctrl).
__device__ __forceinline__ float dpp_shr1(float x) {
  return __int_as_float(__builtin_amdgcn_update_dpp(
      0, __float_as_int(x), 0x138, 0xf, 0xf, true));
}
__device__ __forceinline__ float dpp_shr2(float x) {   // lanes 0,1 -> 0
  return dpp_shr1(dpp_shr1(x));
}

// 16-lane rotate-reduce sum via DPP row_ror (pure VALU).
__device__ __forceinline__ float rowsum16(float s) {
  s += __int_as_float(__builtin_amdgcn_update_dpp(0, __float_as_int(s), 0x121, 0xf, 0xf, false));
  s += __int_as_float(__builtin_amdgcn_update_dpp(0, __float_as_int(s), 0x122, 0xf, 0xf, false));
  s += __int_as_float(__builtin_amdgcn_update_dpp(0, __float_as_int(s), 0x124, 0xf, 0xf, false));
  s += __int_as_float(__builtin_amdgcn_update_dpp(0, __float_as_int(s), 0x128, 0xf, 0xf, false));
  return s;
}

// 16-lane rotate-reduce max via DPP row_ror.
__device__ __forceinline__ float rowmax16(float v) {
  v = fmaxf(v, __int_as_float(__builtin_amdgcn_update_dpp(0, __float_as_int(v), 0x121, 0xf, 0xf, false)));
  v = fmaxf(v, __int_as_float(__builtin_amdgcn_update_dpp(0, __float_as_int(v), 0x122, 0xf, 0xf, false)));
  v = fmaxf(v, __int_as_float(__builtin_amdgcn_update_dpp(0, __float_as_int(v), 0x124, 0xf, 0xf, false)));
  v = fmaxf(v, __int_as_float(__builtin_amdgcn_update_dpp(0, __float_as_int(v), 0x128, 0xf, 0xf, false)));
  return v;
}

__device__ __forceinline__ bfu16 f2bf(float f) {
  unsigned int x = __float_as_uint(f);
  x = x + 0x7fffu + ((x >> 16) & 1u);   // RNE (inputs are finite normals)
  return (bfu16)(x >> 16);
}

__device__ __forceinline__ void async16(const void* g, void* l) {
  __builtin_amdgcn_global_load_lds(
      (__attribute__((address_space(1))) void*)(g),
      (__attribute__((address_space(3))) void*)(l), 16, 0, 0);
}

// ---------- kernel 1: fp32 -> bf16 convert + zero output ----------
__global__ void convert_zero(const float4* __restrict__ hs4,
                             const float4* __restrict__ W4,
                             ushort4* __restrict__ hsb4,
                             ushort4* __restrict__ Wb4,
                             float* __restrict__ out) {
  if (blockIdx.x == 0 && threadIdx.x == 0) out[0] = 0.f;
  const int HS4 = (Nn * Tt * IDIM) / 4;        // 2097152
  const int TOT = HS4 + (Vv * IDIM) / 4;       // +524288
  for (int i = blockIdx.x * 256 + threadIdx.x; i < TOT; i += gridDim.x * 256) {
    float4 f;
    if (i < HS4) f = hs4[i]; else f = W4[i - HS4];
    ushort4 o;
    o.x = f2bf(f.x); o.y = f2bf(f.y); o.z = f2bf(f.z); o.w = f2bf(f.w);
    if (i < HS4) hsb4[i] = o; else Wb4[i - HS4] = o;
  }
}

// ---------- kernel 2: label position lists + skip flags ----------
// poscnt[n][v]  = #positions j (0..127) with ys[n][j]==v
// poslist[n][v][0..15] = those positions (cap 16; P(>16 dups) ~ 0)
__global__ void build_labels(const int* __restrict__ ys,
                             int* __restrict__ poscnt,
                             int* __restrict__ poslist,
                             int* __restrict__ skipflag) {
  const int n = blockIdx.x, tid = threadIdx.x;
  int* pc = poscnt + n * Vv;
  for (int v = tid; v < Vv; v += 256) pc[v] = 0;
  __syncthreads();
  if (tid == 0) {
    int* pl_ = poslist + (size_t)n * Vv * 16;
    for (int j = 0; j < Ss; j++) {
      int v = ys[n * Ss + j];
      int k = pc[v];
      if (k < 16) pl_[v * 16 + k] = j;
      pc[v] = k + 1;
    }
  }
  for (int s = tid; s < Ll; s += 256) {
    int allow = 0;
    if ((s & 1) && s >= 3)
      allow = (ys[n * Ss + ((s - 1) >> 1)] != ys[n * Ss + ((s - 3) >> 1)]) ? 1 : 0;
    skipflag[n * Ll + s] = allow;
  }
}

// ---------- kernel 3: 256x256 BK=64 8-wave MFMA GEMM fused with lse + label scatter ----
// R21 K-loop (verified 78us) unchanged. Epilogue writes:
//  - blank column (c==0) -> plabT[n][0][t] (uniform row for the DP)
//  - label columns -> pkP[n][t][pos] for each label position pos with ys[pos]==c
//    (position-ordered layout; the DP reads it COALESCED: lane l <- pos 2l,2l+1)
__global__ __launch_bounds__(512, 2) void gemm_lse(
    const bfu16* __restrict__ A,      // [16384][512] hs bf16
    const bfu16* __restrict__ B,      // [4096][512]  W  bf16 (B^T layout)
    const float* __restrict__ bias,   // [4096]
    const int*   __restrict__ poscnt, // [16][4096]
    const int*   __restrict__ poslist,// [16][4096][16]
    float* __restrict__ plabT,        // [16][132][1024]  (row 0 = blank)
    float* __restrict__ pkP,          // [16][1024][128]  label probs, position order
    float* __restrict__ psum) {       // [64][16384]  sum of exp2(logit*L2E) partials
  __shared__ alignas(128) char ldsraw[131072];   // [buf][A/B][32KB]
  const int tid  = threadIdx.x;
  const int lane = tid & 63, wid = tid >> 6;     // 8 waves
  const int wr = wid >> 2, wc = wid & 3;         // 2M x 4N wave grid

  // bijective XCD swizzle (1024 % 8 == 0)
  const int flat = blockIdx.x;
  const int wg   = (flat & 7) * 128 + (flat >> 3);
  const int bR = wg >> 4, bC = wg & 15;
  const int rowbase = bR * 256, colbase = bC * 256;

  f32x4 acc[8][4];
#pragma unroll
  for (int m = 0; m < 8; m++)
#pragma unroll
    for (int n = 0; n < 4; n++) {
      f32x4 z = {0.f, 0.f, 0.f, 0.f};
      acc[m][n] = z;
    }

  // ---- staging setup: waves 0-3 stage A (64 rows each), 4-7 stage B ----
  const int  sw  = wid & 3;
  const bool isB = wid >= 4;
  const char* gsrc0 = (const char*)(isB ? (const void*)B : (const void*)A)
      + (size_t)((isB ? colbase : rowbase) + sw * 64 + (lane >> 3)) * (IDIM * 2)
      + (((lane & 7) ^ ((lane >> 3) & 7)) * 16);     // pre-swizzled source chunk
  char* ldst0 = ldsraw + (isB ? 32768 : 0) + sw * 8192;

  // ---- fragment-read setup ----
  const int fr = lane & 15;          // fragment row (A row / B col low bits)
  const int g  = lane >> 4;          // k-chunk 0..3 within K=32 half
  const int fx = fr & 7;             // row&7 for the XOR swizzle

  // epilogue metadata (prefetched; latency hidden under K-loop)
  const int nsamp = bR >> 2;         // 4 row-blocks (256) per sample (1024)
  const int* pcn = poscnt + nsamp * Vv;
  const int* pln = poslist + (size_t)nsamp * Vv * 16;
  float* plT  = plabT + (size_t)nsamp * PST;
  float* pk_n = pkP + (size_t)nsamp * PKS;
  float bc[4];
  int   col[4], cntc[4];
#pragma unroll
  for (int n = 0; n < 4; n++) {
    int c = colbase + wc * 64 + n * 16 + fr;
    col[n]  = c;
    bc[n]   = bias[c];
    cntc[n] = pcn[c];                 // 0 for blank (labels exclude 0) and non-labels
  }

  auto stage = [&](int b, int t) {          // full 8-issue stage (prologue)
#pragma unroll
    for (int i = 0; i < 8; ++i)
      async16(gsrc0 + (size_t)t * 128 + i * 8192, ldst0 + b * 65536 + i * 1024);
  };
  auto stage1 = [&](int b, int t, int i) {  // single issue (interleaved)
    async16(gsrc0 + (size_t)t * 128 + (size_t)i * 8192, ldst0 + b * 65536 + i * 1024);
  };

  // prologue: tiles 0 and 1 in flight (8 loads each per wave)
  stage(0, 0);
  stage(1, 1);

  int buf = 0;
  for (int t = 0; t < 8; ++t) {
    if (t < 7) asm volatile("s_waitcnt vmcnt(8)" ::: "memory");
    else       asm volatile("s_waitcnt vmcnt(0)" ::: "memory");
    __builtin_amdgcn_s_barrier();

    const char* Ab = ldsraw + buf * 65536;
    const char* Bb = Ab + 32768;

    short8_t a0[4], a1[4], a2[4], a3[4], b0[4], b1[4];
#pragma unroll
    for (int m = 0; m < 4; m++)
      a0[m] = *(const short8_t*)(Ab + (wr * 128 + m * 16 + fr) * 128 + ((0 + g) ^ fx) * 16);
#pragma unroll
    for (int n = 0; n < 4; n++)
      b0[n] = *(const short8_t*)(Bb + (wc * 64 + n * 16 + fr) * 128 + ((0 + g) ^ fx) * 16);
#pragma unroll
    for (int m = 0; m < 4; m++)
      a1[m] = *(const short8_t*)(Ab + (wr * 128 + (m + 4) * 16 + fr) * 128 + ((0 + g) ^ fx) * 16);

    __builtin_amdgcn_s_setprio(1);
#pragma unroll
    for (int m = 0; m < 4; m++)
#pragma unroll
      for (int n = 0; n < 4; n++)
        acc[m][n] = __builtin_amdgcn_mfma_f32_16x16x32_bf16(a0[m], b0[n], acc[m][n], 0, 0, 0);
    __builtin_amdgcn_s_setprio(0);

#pragma unroll
    for (int m = 0; m < 4; m++)
      a2[m] = *(const short8_t*)(Ab + (wr * 128 + m * 16 + fr) * 128 + ((4 + g) ^ fx) * 16);
#pragma unroll
    for (int n = 0; n < 4; n++)
      b1[n] = *(const short8_t*)(Bb + (wc * 64 + n * 16 + fr) * 128 + ((4 + g) ^ fx) * 16);

    __builtin_amdgcn_s_setprio(1);
#pragma unroll
    for (int m = 0; m < 4; m++)
#pragma unroll
      for (int n = 0; n < 4; n++)
        acc[m + 4][n] = __builtin_amdgcn_mfma_f32_16x16x32_bf16(a1[m], b0[n], acc[m + 4][n], 0, 0, 0);
    __builtin_amdgcn_s_setprio(0);

#pragma unroll
    for (int m = 0; m < 4; m++)
      a3[m] = *(const short8_t*)(Ab + (wr * 128 + (m + 4) * 16 + fr) * 128 + ((4 + g) ^ fx) * 16);

    // all of this wave's ds_reads of buf issued; drain + sync before overwrite
    asm volatile("s_waitcnt lgkmcnt(0)" ::: "memory");
    __builtin_amdgcn_s_barrier();

    const bool dostage = (t + 2 < 8);
    if (dostage) {
      stage1(buf, t + 2, 0); stage1(buf, t + 2, 1);
      stage1(buf, t + 2, 2); stage1(buf, t + 2, 3);
    }

    __builtin_amdgcn_s_setprio(1);
#pragma unroll
    for (int m = 0; m < 4; m++)
#pragma unroll
      for (int n = 0; n < 4; n++)
        acc[m][n] = __builtin_amdgcn_mfma_f32_16x16x32_bf16(a2[m], b1[n], acc[m][n], 0, 0, 0);
    __builtin_amdgcn_s_setprio(0);

    if (dostage) {
      stage1(buf, t + 2, 4); stage1(buf, t + 2, 5);
      stage1(buf, t + 2, 6); stage1(buf, t + 2, 7);
    }

    __builtin_amdgcn_s_setprio(1);
#pragma unroll
    for (int m = 0; m < 4; m++)
#pragma unroll
      for (int n = 0; n < 4; n++)
        acc[m + 4][n] = __builtin_amdgcn_mfma_f32_16x16x32_bf16(a3[m], b1[n], acc[m + 4][n], 0, 0, 0);
    __builtin_amdgcn_s_setprio(0);

    buf ^= 1;
  }

  // ---- epilogue: bias, blank row + position-ordered label scatter, DPP sums ----
  const int g4 = g * 4;
#pragma unroll
  for (int m = 0; m < 8; m++) {
#pragma unroll
    for (int r = 0; r < 4; r++) {
      int row = rowbase + wr * 128 + m * 16 + g4 + r;
      int tIn = row & 1023;                 // t within sample
      float ev[4];
#pragma unroll
      for (int j = 0; j < 4; j++) {
        float e = fexp2((acc[m][j][r] + bc[j]) * L2E);
        ev[j] = e;
        if (col[j] == 0) plT[tIn] = e;      // blank row (slot 0)
        for (int q2 = 0; q2 < cntc[j]; q2++) {
          int pos = pln[col[j] * 16 + q2];
          pk_n[(size_t)tIn * 128 + pos] = e;
        }
      }
      float s = rowsum16((ev[0] + ev[1]) + (ev[2] + ev[3]));   // DPP reduce
      if (fr == 0) {
        int pc = bC * 4 + wc;             // 0..63
        psum[(size_t)pc * 16384 + row] = s;
      }
    }
  }
}

// ---------- kernel 4: reduce 64 sumexp2 partials per row -> lse (natural log) ----------
__global__ void lse_reduce(const float* __restrict__ psum,
                           float* __restrict__ lse) {
  int row = blockIdx.x * 256 + threadIdx.x;
  float s = 0.f;
#pragma unroll 8
  for (int j = 0; j < 64; j++)
    s += psum[(size_t)j * 16384 + row];
  lse[row] = flog2(s) * LN2;
}

// ---------- kernel 5: CTC forward DP, one wave per sample ----------
// LINEAR-domain, QUAD-step-batched, DPP lane shifts. R22: label probs read
// COALESCED from pkP[n][t][128] — lane l loads float2 {pos 2l, 2l+1} =
// {p(state 4l+1), p(state 4l+3)} (8 transactions/load vs 64-way gather).
__global__ __launch_bounds__(64) void ctc_dp(
    const float* __restrict__ plabT, const float* __restrict__ pkP,
    const float* __restrict__ lse, const int* __restrict__ skipflag,
    const int* __restrict__ hlens, const int* __restrict__ ylens,
    float* __restrict__ out) {
  __shared__ float alf[264];
  const int n    = blockIdx.x;
  const int lane = threadIdx.x;
  const int hlen = hlens[n];
  const int Ln   = 2 * ylens[n] + 1;
  const int sbase = lane * 4;   // states sbase..sbase+3; lane 63 also owns s=256

  const float sk1 = skipflag[n * Ll + sbase + 1] ? 1.f : 0.f;
  const float sk3 = skipflag[n * Ll + sbase + 3] ? 1.f : 0.f;
  const float skh = (lane > 0 && skipflag[n * Ll + sbase - 1]) ? 1.f : 0.f;  // s-1
  const float skz = (lane > 0 && skipflag[n * Ll + sbase - 3]) ? 1.f : 0.f;  // s-3
  const float skv = (lane > 1 && skipflag[n * Ll + sbase - 5]) ? 1.f : 0.f;  // s-5
  const bool  l0  = (lane == 0);
  // validity masks (applied only at rescale)
  const float m0  = (sbase + 0 < Ln) ? 1.f : 0.f;
  const float m1  = (sbase + 1 < Ln) ? 1.f : 0.f;
  const float m2  = (sbase + 2 < Ln) ? 1.f : 0.f;
  const float m3  = (sbase + 3 < Ln) ? 1.f : 0.f;
  const float m4  = (lane == 63 && Ln == 257) ? 1.f : 0.f;

  const float*  rb  = plabT + (size_t)n * PST;       // blank row (slot 0)
  const float2* pk2 = (const float2*)(pkP + (size_t)n * PKS);  // [t][64] float2
  const float*  lsp = lse + n * Tt;

  // sum of lse over t < hlen
  float slse = 0.f;
#pragma unroll
  for (int j = 0; j < 16; j++) {
    int t = lane + 64 * j;
    float v = lsp[t];
    slse += (t < hlen) ? v : 0.f;
  }
#pragma unroll
  for (int off = 32; off; off >>= 1) slse += __shfl_xor(slse, off);

  // t = 0 init: alpha[0] = p_blank(0), alpha[1] = p_y1(0) (pos 0 = lane0's .x)
  float2 w0 = pk2[lane];
  float a0 = 0.f, a1 = 0.f, a2 = 0.f, a3 = 0.f, a4 = 0.f;
  if (l0) { a0 = rb[0]; a1 = w0.x; }

  int sc = 0;   // accumulated log2 scale (true alpha = stored * 2^sc)

  auto step1 = [&](float pb, float p1, float p3) {
    float pm1 = dpp_shr1(a3);          // alpha[sbase-1], lane0 -> 0
    float n4 = (a4 + a3) * pb;
    float n3 = (a3 + a2 + sk3 * a1) * p3;
    float n2 = (a2 + a1) * pb;
    float n1 = (a1 + a0 + sk1 * pm1) * p1;
    float n0 = (a0 + pm1) * pb;
    a0 = n0; a1 = n1; a2 = n2; a3 = n3; a4 = n4;
  };

  auto pair2 = [&](float pbA, float p1A, float p3A,
                   float pbB, float p1B, float p3B) {
    float pa3 = dpp_shr1(a3);
    float pa2 = dpp_shr1(a2);
    float pa1 = dpp_shr1(a1);
    float prA = dpp_shr1(p3A);
    float h1 = (pa3 + pa2 + skh * pa1) * prA;
    float s4 = (a4 + a3) * pbA;
    float s3 = (a3 + a2 + sk3 * a1) * p3A;
    float s2 = (a2 + a1) * pbA;
    float s1 = (a1 + a0 + sk1 * pa3) * p1A;
    float s0 = (a0 + pa3) * pbA;
    a4 = (s4 + s3) * pbB;
    a3 = (s3 + s2 + sk3 * s1) * p3B;
    a2 = (s2 + s1) * pbB;
    a1 = (s1 + s0 + sk1 * h1) * p1B;
    a0 = (s0 + h1) * pbB;
  };

  auto rescale = [&]() {
    a0 *= m0; a1 *= m1; a2 *= m2; a3 *= m3; a4 *= m4;   // mask garbage (R9 fix)
    float mx = fmaxf(fmaxf(a0, a1), fmaxf(a2, a3));
    mx = fmaxf(mx, a4);
    mx = rowmax16(mx);
    mx = fmaxf(mx, __shfl_xor(mx, 16));
    mx = fmaxf(mx, __shfl_xor(mx, 32));
    int ee = (int)((__float_as_uint(mx) >> 23) & 0xff) - 127;
    ee = (mx > 0.f) ? ee : 0;
    float s = __uint_as_float((unsigned)(127 - ee) << 23);
    sc += ee;
    a0 *= s; a1 *= s; a2 *= s; a3 *= s; a4 *= s;
  };

  // ---- superblock (16 steps) register ring, double-buffered ----
  float pb_[2][4][4];                 // blank per (quad,row)
  float p1f[2][16], p3f[2][16];       // label probs per row (coalesced loads)
  float hx_[2][4][3], hz_[2][4][2], hv_[2][4];

  auto loadSB = [&](int sl, int t4) {
#pragma unroll
    for (int q = 0; q < 4; q++) {
      float4 vb = *(const float4*)(rb + t4 + 4 * q);
      pb_[sl][q][0] = vb.x; pb_[sl][q][1] = vb.y; pb_[sl][q][2] = vb.z; pb_[sl][q][3] = vb.w;
    }
#pragma unroll
    for (int i = 0; i < 16; i++) {
      float2 w = pk2[(size_t)(t4 + i) * 64 + lane];
      p1f[sl][i] = w.x; p3f[sl][i] = w.y;
    }
  };

  auto haloSB = [&](int sl) {
#pragma unroll
    for (int q = 0; q < 4; q++) {
      hx_[sl][q][0] = dpp_shr1(p3f[sl][4 * q + 0]);
      hx_[sl][q][1] = dpp_shr1(p3f[sl][4 * q + 1]);
      hx_[sl][q][2] = dpp_shr1(p3f[sl][4 * q + 2]);
      hz_[sl][q][0] = dpp_shr1(p1f[sl][4 * q + 0]);
      hz_[sl][q][1] = dpp_shr1(p1f[sl][4 * q + 1]);
      hv_[sl][q]    = dpp_shr2(p3f[sl][4 * q + 0]);
    }
  };

  auto quadsSB = [&](int sl) {
#pragma unroll
    for (int q = 0; q < 4; q++) {
      float x0 = dpp_shr1(a3);
      float y0 = dpp_shr1(a2);
      float z0 = dpp_shr1(a1);
      float w0_ = dpp_shr1(a0);
      float v0 = dpp_shr2(a3);
      float u0 = dpp_shr2(a2);
      float q0 = dpp_shr2(a1);

      float v1 = (v0 + u0 + skv * q0) * hv_[sl][q];
      float w1 = (w0_ + v0) * pb_[sl][q][0];
      float z1 = (z0 + w0_ + skz * v0) * hz_[sl][q][0];
      float y1 = (y0 + z0) * pb_[sl][q][0];
      float x1 = (x0 + y0 + skh * z0) * hx_[sl][q][0];
      float z2 = (z1 + w1 + skz * v1) * hz_[sl][q][1];
      float y2 = (y1 + z1) * pb_[sl][q][1];
      float x2 = (x1 + y1 + skh * z1) * hx_[sl][q][1];
      float x3 = (x2 + y2 + skh * z2) * hx_[sl][q][2];

      float xk[4] = {x0, x1, x2, x3};
#pragma unroll
      for (int r = 0; r < 4; r++) {
        float pb = pb_[sl][q][r], p1v = p1f[sl][4 * q + r], p3v = p3f[sl][4 * q + r];
        float n4 = (a4 + a3) * pb;
        float n3 = (a3 + a2 + sk3 * a1) * p3v;
        float n2 = (a2 + a1) * pb;
        float n1 = (a1 + a0 + sk1 * xk[r]) * p1v;
        float n0 = (a0 + xk[r]) * pb;
        a0 = n0; a1 = n1; a2 = n2; a3 = n3; a4 = n4;
      }
    }
  };

  const int nsteps = hlen - 1;        // steps consume rows 1..hlen-1

  // startup singles t=1..3 (align superblocks to t%4==0)
  int t = 1;
  while (t < 4 && t <= nsteps) {
    float2 w = pk2[(size_t)t * 64 + lane];
    step1(rb[t], w.x, w.y);
    ++t;
  }

  const int nSB = (nsteps >= 19) ? (nsteps - 3) / 16 : 0;   // superblocks from t=4
  int t4 = 4;
  if (nSB > 0) loadSB(0, t4);

  int done = 0;
  while (done + 2 <= nSB) {
    if (done + 1 < nSB) loadSB(1, t4 + 16);
    haloSB(0); quadsSB(0);
    if (done + 2 < nSB) loadSB(0, t4 + 32);
    haloSB(1); quadsSB(1);
    rescale();                        // every 32 steps
    done += 2; t4 += 32;
  }
  if (done < nSB) {                   // odd leftover superblock (data in slot 0)
    haloSB(0); quadsSB(0);
    rescale();
    t4 += 16;
  }
  t = 4 + 16 * nSB;

  // tail: pairs then single (direct coalesced loads)
  for (; t + 1 <= nsteps; t += 2) {
    float2 wA = pk2[(size_t)t * 64 + lane];
    float2 wB = pk2[(size_t)(t + 1) * 64 + lane];
    pair2(rb[t], wA.x, wA.y, rb[t + 1], wB.x, wB.y);
  }
  if (t <= nsteps) {
    float2 w = pk2[(size_t)t * 64 + lane];
    step1(rb[t], w.x, w.y);
  }
  rescale();                          // final mask + normalize before readout

  alf[sbase + 0] = a0; alf[sbase + 1] = a1;
  alf[sbase + 2] = a2; alf[sbase + 3] = a3;
  if (lane == 63) alf[256] = a4;
  __syncthreads();
  if (l0) {
    float sum = alf[Ln - 1] + alf[Ln - 2];
    float per = 0.f;
    if (sum > 0.f) {
      float llv = (flog2(sum) + (float)sc) * LN2 - slse;
      if (llv > -1e29f) per = -llv;
    }
    atomicAdd(out, per * (1.0f / 16.0f));
  }
}

// ---------- launcher ----------
extern "C" void kernel_launch(void* const* d_in, const int* in_sizes, int n_in,
                              void* d_out, int out_size, void* d_ws, size_t ws_size,
                              hipStream_t stream) {
  const float* hs    = (const float*)d_in[0];
  const int*   hlens = (const int*)d_in[1];
  const int*   ys    = (const int*)d_in[2];
  const int*   ylens = (const int*)d_in[3];
  const float* W     = (const float*)d_in[4];
  const float* bias  = (const float*)d_in[5];
  float*       out   = (float*)d_out;
  char*        ws    = (char*)d_ws;

  // workspace carve (bytes)
  const size_t off_hsb    = 0;                               // 16,777,216
  const size_t off_Wb     = off_hsb    + (size_t)Nn*Tt*IDIM*2;
  const size_t off_plab   = off_Wb     + (size_t)Vv*IDIM*2;  // 8,650,752
  const size_t off_pkP    = off_plab   + (size_t)Nn*LS*Tt*4; // 8,388,608
  const size_t off_psum   = off_pkP    + (size_t)Nn*Tt*128*4;
  const size_t off_lse    = off_psum   + (size_t)64*16384*4;
  const size_t off_poscnt = off_lse    + (size_t)16384*4;
  const size_t off_poslist= off_poscnt + (size_t)Nn*Vv*4;
  const size_t off_skip   = off_poslist+ (size_t)Nn*Vv*16*4;

  bfu16* hsb    = (bfu16*)(ws + off_hsb);
  bfu16* Wb     = (bfu16*)(ws + off_Wb);
  float* plabT  = (float*)(ws + off_plab);
  float* pkP    = (float*)(ws + off_pkP);
  float* psum   = (float*)(ws + off_psum);
  float* lse    = (float*)(ws + off_lse);
  int*   poscnt = (int*)(ws + off_poscnt);
  int*   poslist= (int*)(ws + off_poslist);
  int*   skipf  = (int*)(ws + off_skip);

  convert_zero<<<2048, 256, 0, stream>>>(
      (const float4*)hs, (const float4*)W, (ushort4*)hsb, (ushort4*)Wb, out);
  build_labels<<<16, 256, 0, stream>>>(ys, poscnt, poslist, skipf);
  gemm_lse<<<1024, 512, 0, stream>>>(hsb, Wb, bias, poscnt, poslist, plabT, pkP, psum);
  lse_reduce<<<64, 256, 0, stream>>>(psum, lse);
  ctc_dp<<<16, 64, 0, stream>>>(plabT, pkP, lse, skipf, hlens, ylens, out);
}

// Round 23
// 182.193 us; speedup vs baseline: 1.4718x; 1.4718x over previous
//
#include <hip/hip_runtime.h>
#include <cstdint>
#include <cstddef>

// ---------- types ----------
using short8_t = __attribute__((ext_vector_type(8))) short;
using f32x4    = __attribute__((ext_vector_type(4))) float;
typedef unsigned short bfu16;

constexpr int   Nn   = 16;
constexpr int   Tt   = 1024;
constexpr int   IDIM = 512;
constexpr int   Vv   = 4096;
constexpr int   Ss   = 128;
constexpr int   Ll   = 2 * Ss + 1;   // 257
constexpr int   LS   = 132;          // plabT slot count (row 0 = blank)
constexpr int   PST  = LS * Tt;      // per-sample plabT stride (floats)
constexpr int   PKS  = Tt * 128;     // per-sample pkP stride (floats)
constexpr float NEGV = -1e30f;
constexpr float L2E  = 1.4426950408889634f;  // log2(e)
constexpr float LN2  = 0.6931471805599453f;  // ln(2)

// ---------- helpers ----------
__device__ __forceinline__ float fexp2(float x) { return __builtin_amdgcn_exp2f(x); }
__device__ __forceinline__ float flog2(float x) { return __builtin_amdgcn_logf(x); }

// DPP wave_shr:1 lane shift (lane i <- lane i-1), lane 0 -> 0 (bound_ctrl).
__device__ __forceinline__ float dpp_shr1(float x) {
  return __int_as_float(__builtin_amdgcn_update_dpp(
      0, __float_as_int(x), 0x138, 0xf, 0xf, true));
}
__device__ __forceinline__ float dpp_shr2(float x) {   // lanes 0,1 -> 0
  return dpp_shr1(dpp_shr1(x));
}

// 16-lane rotate-reduce sum via DPP row_ror (pure VALU).
__device__ __forceinline__ float rowsum16(float s) {
  s += __int_as_float(__builtin_amdgcn_update_dpp(0, __float_as_int(s), 0x121, 0xf, 0xf, false));
  s += __int_as_float(__builtin_amdgcn_update_dpp(0, __float_as_int(s), 0x122, 0xf, 0xf, false));
  s += __int_as_float(__builtin_amdgcn_update_dpp(0, __float_as_int(s), 0x124, 0xf, 0xf, false));
  s += __int_as_float(__builtin_amdgcn_update_dpp(0, __float_as_int(s), 0x128, 0xf, 0xf, false));
  return s;
}

// 16-lane rotate-reduce max via DPP row_ror.
__device__ __forceinline__ float rowmax16(float v) {
  v = fmaxf(v, __int_as_float(__builtin_amdgcn_update_dpp(0, __float_as_int(v), 0x121, 0xf, 0xf, false)));
  v = fmaxf(v, __int_as_float(__builtin_amdgcn_update_dpp(0, __float_as_int(v), 0x122, 0xf, 0xf, false)));
  v = fmaxf(v, __int_as_float(__builtin_amdgcn_update_dpp(0, __float_as_int(v), 0x124, 0xf, 0xf, false)));
  v = fmaxf(v, __int_as_float(__builtin_amdgcn_update_dpp(0, __float_as_int(v), 0x128, 0xf, 0xf, false)));
  return v;
}

__device__ __forceinline__ bfu16 f2bf(float f) {
  unsigned int x = __float_as_uint(f);
  x = x + 0x7fffu + ((x >> 16) & 1u);   // RNE (inputs are finite normals)
  return (bfu16)(x >> 16);
}

__device__ __forceinline__ void async16(const void* g, void* l) {
  __builtin_amdgcn_global_load_lds(
      (__attribute__((address_space(1))) void*)(g),
      (__attribute__((address_space(3))) void*)(l), 16, 0, 0);
}

// ---------- kernel 1: fp32 -> bf16 convert + zero output ----------
__global__ void convert_zero(const float4* __restrict__ hs4,
                             const float4* __restrict__ W4,
                             ushort4* __restrict__ hsb4,
                             ushort4* __restrict__ Wb4,
                             float* __restrict__ out) {
  if (blockIdx.x == 0 && threadIdx.x == 0) out[0] = 0.f;
  const int HS4 = (Nn * Tt * IDIM) / 4;        // 2097152
  const int TOT = HS4 + (Vv * IDIM) / 4;       // +524288
  for (int i = blockIdx.x * 256 + threadIdx.x; i < TOT; i += gridDim.x * 256) {
    float4 f;
    if (i < HS4) f = hs4[i]; else f = W4[i - HS4];
    ushort4 o;
    o.x = f2bf(f.x); o.y = f2bf(f.y); o.z = f2bf(f.z); o.w = f2bf(f.w);
    if (i < HS4) hsb4[i] = o; else Wb4[i - HS4] = o;
  }
}

// ---------- kernel 2: build label map / extended sequence (R21 version) ----------
__global__ void build_labels(const int* __restrict__ ys,
                             int* __restrict__ labmap,
                             int* __restrict__ extidx,
                             int* __restrict__ skipflag) {
  const int n = blockIdx.x, tid = threadIdx.x;
  int* lm = labmap + n * Vv;
  for (int v = tid; v < Vv; v += 256) lm[v] = 0x7fffffff;
  __syncthreads();
  if (tid == 0) lm[0] = 0;                                  // blank -> slot 0
  if (tid < Ss) atomicMin(&lm[ys[n * Ss + tid]], tid + 1);  // canonical = first occurrence
  __syncthreads();
  for (int s = tid; s < Ll; s += 256) {
    int v = (s & 1) ? ys[n * Ss + ((s - 1) >> 1)] : 0;
    extidx[n * Ll + s] = lm[v];
    int allow = 0;
    if ((s & 1) && s >= 3) allow = (v != ys[n * Ss + ((s - 3) >> 1)]) ? 1 : 0;
    skipflag[n * Ll + s] = allow;
  }
  __syncthreads();
  for (int v = tid; v < Vv; v += 256)
    if (lm[v] == 0x7fffffff) lm[v] = -1;
}

// ---------- kernel 2b: LDS-transpose scatter plabT -> pkP[n][t][128] ----------
// Per (sample, 64-t tile): gather the 128 label-position rows (reads coalesced
// in t), transpose via padded LDS tile, write pkP coalesced (512B rows).
__global__ __launch_bounds__(256) void build_pkP(
    const float* __restrict__ plabT, const int* __restrict__ extidx,
    float* __restrict__ pkP) {
  __shared__ float tile[128][65];     // pad 65: conflict-free both sides
  __shared__ int spos[128];
  const int n   = blockIdx.x >> 4;    // 16 t-tiles per sample
  const int t0  = (blockIdx.x & 15) * 64;
  const int tid = threadIdx.x;
  if (tid < 128) spos[tid] = extidx[n * Ll + 2 * tid + 1];   // slot of position tid
  __syncthreads();
  const float* pl = plabT + (size_t)n * PST;
  const int lane = tid & 63, w = tid >> 6;      // 4 waves
  for (int p = w; p < 128; p += 4)
    tile[p][lane] = pl[(size_t)spos[p] * Tt + t0 + lane];
  __syncthreads();
  float* dst = pkP + (size_t)n * PKS + (size_t)t0 * 128;
  const int pos = tid & 127, half = tid >> 7;   // 2 t-rows per iteration
  for (int i = 0; i < 64; i += 2) {
    int t = i + half;
    dst[(size_t)t * 128 + pos] = tile[pos][t];
  }
}

// ---------- kernel 3: 256x256 BK=64 8-wave MFMA GEMM fused with lse + label scatter ----
// R21 version (verified 78us): counted-vmcnt + early read-barrier + stage
// interleave between MFMA quadrants; plabT slot scatter; DPP row_ror reduce.
__global__ __launch_bounds__(512, 2) void gemm_lse(
    const bfu16* __restrict__ A,      // [16384][512] hs bf16
    const bfu16* __restrict__ B,      // [4096][512]  W  bf16 (B^T layout)
    const float* __restrict__ bias,   // [4096]
    const int*   __restrict__ labmap, // [16][4096]
    float* __restrict__ plabT,        // [16][132][1024]  exp2(logit*L2E), transposed
    float* __restrict__ psum) {       // [64][16384]  sum of exp2(logit*L2E) partials
  __shared__ alignas(128) char ldsraw[131072];   // [buf][A/B][32KB]
  const int tid  = threadIdx.x;
  const int lane = tid & 63, wid = tid >> 6;     // 8 waves
  const int wr = wid >> 2, wc = wid & 3;         // 2M x 4N wave grid

  // bijective XCD swizzle (1024 % 8 == 0)
  const int flat = blockIdx.x;
  const int wg   = (flat & 7) * 128 + (flat >> 3);
  const int bR = wg >> 4, bC = wg & 15;
  const int rowbase = bR * 256, colbase = bC * 256;

  f32x4 acc[8][4];
#pragma unroll
  for (int m = 0; m < 8; m++)
#pragma unroll
    for (int n = 0; n < 4; n++) {
      f32x4 z = {0.f, 0.f, 0.f, 0.f};
      acc[m][n] = z;
    }

  // ---- staging setup: waves 0-3 stage A (64 rows each), 4-7 stage B ----
  const int  sw  = wid & 3;
  const bool isB = wid >= 4;
  const char* gsrc0 = (const char*)(isB ? (const void*)B : (const void*)A)
      + (size_t)((isB ? colbase : rowbase) + sw * 64 + (lane >> 3)) * (IDIM * 2)
      + (((lane & 7) ^ ((lane >> 3) & 7)) * 16);     // pre-swizzled source chunk
  char* ldst0 = ldsraw + (isB ? 32768 : 0) + sw * 8192;

  // ---- fragment-read setup ----
  const int fr = lane & 15;          // fragment row (A row / B col low bits)
  const int g  = lane >> 4;          // k-chunk 0..3 within K=32 half
  const int fx = fr & 7;             // row&7 for the XOR swizzle

  // epilogue metadata (prefetched; latency hidden under K-loop)
  const int nsamp = bR >> 2;         // 4 row-blocks (256) per sample (1024)
  const int* lm = labmap + nsamp * Vv;
  float* plT = plabT + (size_t)nsamp * PST;
  float bc[4];
  int   slot[4];
#pragma unroll
  for (int n = 0; n < 4; n++) {
    int c = colbase + wc * 64 + n * 16 + fr;
    bc[n]   = bias[c];
    slot[n] = lm[c];
  }

  auto stage = [&](int b, int t) {          // full 8-issue stage (prologue)
#pragma unroll
    for (int i = 0; i < 8; ++i)
      async16(gsrc0 + (size_t)t * 128 + i * 8192, ldst0 + b * 65536 + i * 1024);
  };
  auto stage1 = [&](int b, int t, int i) {  // single issue (interleaved)
    async16(gsrc0 + (size_t)t * 128 + (size_t)i * 8192, ldst0 + b * 65536 + i * 1024);
  };

  // prologue: tiles 0 and 1 in flight (8 loads each per wave)
  stage(0, 0);
  stage(1, 1);

  int buf = 0;
  for (int t = 0; t < 8; ++t) {
    if (t < 7) asm volatile("s_waitcnt vmcnt(8)" ::: "memory");
    else       asm volatile("s_waitcnt vmcnt(0)" ::: "memory");
    __builtin_amdgcn_s_barrier();

    const char* Ab = ldsraw + buf * 65536;
    const char* Bb = Ab + 32768;

    short8_t a0[4], a1[4], a2[4], a3[4], b0[4], b1[4];
#pragma unroll
    for (int m = 0; m < 4; m++)
      a0[m] = *(const short8_t*)(Ab + (wr * 128 + m * 16 + fr) * 128 + ((0 + g) ^ fx) * 16);
#pragma unroll
    for (int n = 0; n < 4; n++)
      b0[n] = *(const short8_t*)(Bb + (wc * 64 + n * 16 + fr) * 128 + ((0 + g) ^ fx) * 16);
#pragma unroll
    for (int m = 0; m < 4; m++)
      a1[m] = *(const short8_t*)(Ab + (wr * 128 + (m + 4) * 16 + fr) * 128 + ((0 + g) ^ fx) * 16);

    __builtin_amdgcn_s_setprio(1);
#pragma unroll
    for (int m = 0; m < 4; m++)
#pragma unroll
      for (int n = 0; n < 4; n++)
        acc[m][n] = __builtin_amdgcn_mfma_f32_16x16x32_bf16(a0[m], b0[n], acc[m][n], 0, 0, 0);
    __builtin_amdgcn_s_setprio(0);

#pragma unroll
    for (int m = 0; m < 4; m++)
      a2[m] = *(const short8_t*)(Ab + (wr * 128 + m * 16 + fr) * 128 + ((4 + g) ^ fx) * 16);
#pragma unroll
    for (int n = 0; n < 4; n++)
      b1[n] = *(const short8_t*)(Bb + (wc * 64 + n * 16 + fr) * 128 + ((4 + g) ^ fx) * 16);

    __builtin_amdgcn_s_setprio(1);
#pragma unroll
    for (int m = 0; m < 4; m++)
#pragma unroll
      for (int n = 0; n < 4; n++)
        acc[m + 4][n] = __builtin_amdgcn_mfma_f32_16x16x32_bf16(a1[m], b0[n], acc[m + 4][n], 0, 0, 0);
    __builtin_amdgcn_s_setprio(0);

#pragma unroll
    for (int m = 0; m < 4; m++)
      a3[m] = *(const short8_t*)(Ab + (wr * 128 + (m + 4) * 16 + fr) * 128 + ((4 + g) ^ fx) * 16);

    // all of this wave's ds_reads of buf issued; drain + sync before overwrite
    asm volatile("s_waitcnt lgkmcnt(0)" ::: "memory");
    __builtin_amdgcn_s_barrier();

    const bool dostage = (t + 2 < 8);
    if (dostage) {
      stage1(buf, t + 2, 0); stage1(buf, t + 2, 1);
      stage1(buf, t + 2, 2); stage1(buf, t + 2, 3);
    }

    __builtin_amdgcn_s_setprio(1);
#pragma unroll
    for (int m = 0; m < 4; m++)
#pragma unroll
      for (int n = 0; n < 4; n++)
        acc[m][n] = __builtin_amdgcn_mfma_f32_16x16x32_bf16(a2[m], b1[n], acc[m][n], 0, 0, 0);
    __builtin_amdgcn_s_setprio(0);

    if (dostage) {
      stage1(buf, t + 2, 4); stage1(buf, t + 2, 5);
      stage1(buf, t + 2, 6); stage1(buf, t + 2, 7);
    }

    __builtin_amdgcn_s_setprio(1);
#pragma unroll
    for (int m = 0; m < 4; m++)
#pragma unroll
      for (int n = 0; n < 4; n++)
        acc[m + 4][n] = __builtin_amdgcn_mfma_f32_16x16x32_bf16(a3[m], b1[n], acc[m + 4][n], 0, 0, 0);
    __builtin_amdgcn_s_setprio(0);

    buf ^= 1;
  }

  // ---- epilogue: bias, TRANSPOSED label scatter (exp2'd), DPP-reduced sums ----
  const int g4 = g * 4;
#pragma unroll
  for (int m = 0; m < 8; m++) {
#pragma unroll
    for (int r = 0; r < 4; r++) {
      int row = rowbase + wr * 128 + m * 16 + g4 + r;
      int tIn = row & 1023;                 // t within sample
      float e0 = fexp2((acc[m][0][r] + bc[0]) * L2E);
      float e1 = fexp2((acc[m][1][r] + bc[1]) * L2E);
      float e2 = fexp2((acc[m][2][r] + bc[2]) * L2E);
      float e3 = fexp2((acc[m][3][r] + bc[3]) * L2E);
      if (slot[0] >= 0) plT[(size_t)slot[0] * Tt + tIn] = e0;
      if (slot[1] >= 0) plT[(size_t)slot[1] * Tt + tIn] = e1;
      if (slot[2] >= 0) plT[(size_t)slot[2] * Tt + tIn] = e2;
      if (slot[3] >= 0) plT[(size_t)slot[3] * Tt + tIn] = e3;
      float s = rowsum16((e0 + e1) + (e2 + e3));   // DPP row_ror reduce
      if (fr == 0) {
        int pc = bC * 4 + wc;             // 0..63
        psum[(size_t)pc * 16384 + row] = s;
      }
    }
  }
}

// ---------- kernel 4: reduce 64 sumexp2 partials per row -> lse (natural log) ----------
__global__ void lse_reduce(const float* __restrict__ psum,
                           float* __restrict__ lse) {
  int row = blockIdx.x * 256 + threadIdx.x;
  float s = 0.f;
#pragma unroll 8
  for (int j = 0; j < 64; j++)
    s += psum[(size_t)j * 16384 + row];
  lse[row] = flog2(s) * LN2;
}

// ---------- kernel 5: CTC forward DP, one wave per sample ----------
// LINEAR-domain, QUAD-step-batched, DPP lane shifts (R22 version, verified
// correct): label probs read COALESCED from pkP[n][t][128] — lane l loads
// float2 {pos 2l, 2l+1} = {p(state 4l+1), p(state 4l+3)}.
__global__ __launch_bounds__(64) void ctc_dp(
    const float* __restrict__ plabT, const float* __restrict__ pkP,
    const float* __restrict__ lse, const int* __restrict__ skipflag,
    const int* __restrict__ hlens, const int* __restrict__ ylens,
    float* __restrict__ out) {
  __shared__ float alf[264];
  const int n    = blockIdx.x;
  const int lane = threadIdx.x;
  const int hlen = hlens[n];
  const int Ln   = 2 * ylens[n] + 1;
  const int sbase = lane * 4;   // states sbase..sbase+3; lane 63 also owns s=256

  const float sk1 = skipflag[n * Ll + sbase + 1] ? 1.f : 0.f;
  const float sk3 = skipflag[n * Ll + sbase + 3] ? 1.f : 0.f;
  const float skh = (lane > 0 && skipflag[n * Ll + sbase - 1]) ? 1.f : 0.f;  // s-1
  const float skz = (lane > 0 && skipflag[n * Ll + sbase - 3]) ? 1.f : 0.f;  // s-3
  const float skv = (lane > 1 && skipflag[n * Ll + sbase - 5]) ? 1.f : 0.f;  // s-5
  const bool  l0  = (lane == 0);
  // validity masks (applied only at rescale)
  const float m0  = (sbase + 0 < Ln) ? 1.f : 0.f;
  const float m1  = (sbase + 1 < Ln) ? 1.f : 0.f;
  const float m2  = (sbase + 2 < Ln) ? 1.f : 0.f;
  const float m3  = (sbase + 3 < Ln) ? 1.f : 0.f;
  const float m4  = (lane == 63 && Ln == 257) ? 1.f : 0.f;

  const float*  rb  = plabT + (size_t)n * PST;       // blank row (slot 0)
  const float2* pk2 = (const float2*)(pkP + (size_t)n * PKS);  // [t][64] float2
  const float*  lsp = lse + n * Tt;

  // sum of lse over t < hlen
  float slse = 0.f;
#pragma unroll
  for (int j = 0; j < 16; j++) {
    int t = lane + 64 * j;
    float v = lsp[t];
    slse += (t < hlen) ? v : 0.f;
  }
#pragma unroll
  for (int off = 32; off; off >>= 1) slse += __shfl_xor(slse, off);

  // t = 0 init: alpha[0] = p_blank(0), alpha[1] = p_y1(0) (pos 0 = lane0's .x)
  float2 w0 = pk2[lane];
  float a0 = 0.f, a1 = 0.f, a2 = 0.f, a3 = 0.f, a4 = 0.f;
  if (l0) { a0 = rb[0]; a1 = w0.x; }

  int sc = 0;   // accumulated log2 scale (true alpha = stored * 2^sc)

  auto step1 = [&](float pb, float p1, float p3) {
    float pm1 = dpp_shr1(a3);          // alpha[sbase-1], lane0 -> 0
    float n4 = (a4 + a3) * pb;
    float n3 = (a3 + a2 + sk3 * a1) * p3;
    float n2 = (a2 + a1) * pb;
    float n1 = (a1 + a0 + sk1 * pm1) * p1;
    float n0 = (a0 + pm1) * pb;
    a0 = n0; a1 = n1; a2 = n2; a3 = n3; a4 = n4;
  };

  auto pair2 = [&](float pbA, float p1A, float p3A,
                   float pbB, float p1B, float p3B) {
    float pa3 = dpp_shr1(a3);
    float pa2 = dpp_shr1(a2);
    float pa1 = dpp_shr1(a1);
    float prA = dpp_shr1(p3A);
    float h1 = (pa3 + pa2 + skh * pa1) * prA;
    float s4 = (a4 + a3) * pbA;
    float s3 = (a3 + a2 + sk3 * a1) * p3A;
    float s2 = (a2 + a1) * pbA;
    float s1 = (a1 + a0 + sk1 * pa3) * p1A;
    float s0 = (a0 + pa3) * pbA;
    a4 = (s4 + s3) * pbB;
    a3 = (s3 + s2 + sk3 * s1) * p3B;
    a2 = (s2 + s1) * pbB;
    a1 = (s1 + s0 + sk1 * h1) * p1B;
    a0 = (s0 + h1) * pbB;
  };

  auto rescale = [&]() {
    a0 *= m0; a1 *= m1; a2 *= m2; a3 *= m3; a4 *= m4;   // mask garbage (R9 fix)
    float mx = fmaxf(fmaxf(a0, a1), fmaxf(a2, a3));
    mx = fmaxf(mx, a4);
    mx = rowmax16(mx);
    mx = fmaxf(mx, __shfl_xor(mx, 16));
    mx = fmaxf(mx, __shfl_xor(mx, 32));
    int ee = (int)((__float_as_uint(mx) >> 23) & 0xff) - 127;
    ee = (mx > 0.f) ? ee : 0;
    float s = __uint_as_float((unsigned)(127 - ee) << 23);
    sc += ee;
    a0 *= s; a1 *= s; a2 *= s; a3 *= s; a4 *= s;
  };

  // ---- superblock (16 steps) register ring, double-buffered ----
  float pb_[2][4][4];                 // blank per (quad,row)
  float p1f[2][16], p3f[2][16];       // label probs per row (coalesced loads)
  float hx_[2][4][3], hz_[2][4][2], hv_[2][4];

  auto loadSB = [&](int sl, int t4) {
#pragma unroll
    for (int q = 0; q < 4; q++) {
      float4 vb = *(const float4*)(rb + t4 + 4 * q);
      pb_[sl][q][0] = vb.x; pb_[sl][q][1] = vb.y; pb_[sl][q][2] = vb.z; pb_[sl][q][3] = vb.w;
    }
#pragma unroll
    for (int i = 0; i < 16; i++) {
      float2 w = pk2[(size_t)(t4 + i) * 64 + lane];
      p1f[sl][i] = w.x; p3f[sl][i] = w.y;
    }
  };

  auto haloSB = [&](int sl) {
#pragma unroll
    for (int q = 0; q < 4; q++) {
      hx_[sl][q][0] = dpp_shr1(p3f[sl][4 * q + 0]);
      hx_[sl][q][1] = dpp_shr1(p3f[sl][4 * q + 1]);
      hx_[sl][q][2] = dpp_shr1(p3f[sl][4 * q + 2]);
      hz_[sl][q][0] = dpp_shr1(p1f[sl][4 * q + 0]);
      hz_[sl][q][1] = dpp_shr1(p1f[sl][4 * q + 1]);
      hv_[sl][q]    = dpp_shr2(p3f[sl][4 * q + 0]);
    }
  };

  auto quadsSB = [&](int sl) {
#pragma unroll
    for (int q = 0; q < 4; q++) {
      float x0 = dpp_shr1(a3);
      float y0 = dpp_shr1(a2);
      float z0 = dpp_shr1(a1);
      float w0_ = dpp_shr1(a0);
      float v0 = dpp_shr2(a3);
      float u0 = dpp_shr2(a2);
      float q0 = dpp_shr2(a1);

      float v1 = (v0 + u0 + skv * q0) * hv_[sl][q];
      float w1 = (w0_ + v0) * pb_[sl][q][0];
      float z1 = (z0 + w0_ + skz * v0) * hz_[sl][q][0];
      float y1 = (y0 + z0) * pb_[sl][q][0];
      float x1 = (x0 + y0 + skh * z0) * hx_[sl][q][0];
      float z2 = (z1 + w1 + skz * v1) * hz_[sl][q][1];
      float y2 = (y1 + z1) * pb_[sl][q][1];
      float x2 = (x1 + y1 + skh * z1) * hx_[sl][q][1];
      float x3 = (x2 + y2 + skh * z2) * hx_[sl][q][2];

      float xk[4] = {x0, x1, x2, x3};
#pragma unroll
      for (int r = 0; r < 4; r++) {
        float pb = pb_[sl][q][r], p1v = p1f[sl][4 * q + r], p3v = p3f[sl][4 * q + r];
        float n4 = (a4 + a3) * pb;
        float n3 = (a3 + a2 + sk3 * a1) * p3v;
        float n2 = (a2 + a1) * pb;
        float n1 = (a1 + a0 + sk1 * xk[r]) * p1v;
        float n0 = (a0 + xk[r]) * pb;
        a0 = n0; a1 = n1; a2 = n2; a3 = n3; a4 = n4;
      }
    }
  };

  const int nsteps = hlen - 1;        // steps consume rows 1..hlen-1

  // startup singles t=1..3 (align superblocks to t%4==0)
  int t = 1;
  while (t < 4 && t <= nsteps) {
    float2 w = pk2[(size_t)t * 64 + lane];
    step1(rb[t], w.x, w.y);
    ++t;
  }

  const int nSB = (nsteps >= 19) ? (nsteps - 3) / 16 : 0;   // superblocks from t=4
  int t4 = 4;
  if (nSB > 0) loadSB(0, t4);

  int done = 0;
  while (done + 2 <= nSB) {
    if (done + 1 < nSB) loadSB(1, t4 + 16);
    haloSB(0); quadsSB(0);
    if (done + 2 < nSB) loadSB(0, t4 + 32);
    haloSB(1); quadsSB(1);
    rescale();                        // every 32 steps
    done += 2; t4 += 32;
  }
  if (done < nSB) {                   // odd leftover superblock (data in slot 0)
    haloSB(0); quadsSB(0);
    rescale();
    t4 += 16;
  }
  t = 4 + 16 * nSB;

  // tail: pairs then single (direct coalesced loads)
  for (; t + 1 <= nsteps; t += 2) {
    float2 wA = pk2[(size_t)t * 64 + lane];
    float2 wB = pk2[(size_t)(t + 1) * 64 + lane];
    pair2(rb[t], wA.x, wA.y, rb[t + 1], wB.x, wB.y);
  }
  if (t <= nsteps) {
    float2 w = pk2[(size_t)t * 64 + lane];
    step1(rb[t], w.x, w.y);
  }
  rescale();                          // final mask + normalize before readout

  alf[sbase + 0] = a0; alf[sbase + 1] = a1;
  alf[sbase + 2] = a2; alf[sbase + 3] = a3;
  if (lane == 63) alf[256] = a4;
  __syncthreads();
  if (l0) {
    float sum = alf[Ln - 1] + alf[Ln - 2];
    float per = 0.f;
    if (sum > 0.f) {
      float llv = (flog2(sum) + (float)sc) * LN2 - slse;
      if (llv > -1e29f) per = -llv;
    }
    atomicAdd(out, per * (1.0f / 16.0f));
  }
}

// ---------- launcher ----------
extern "C" void kernel_launch(void* const* d_in, const int* in_sizes, int n_in,
                              void* d_out, int out_size, void* d_ws, size_t ws_size,
                              hipStream_t stream) {
  const float* hs    = (const float*)d_in[0];
  const int*   hlens = (const int*)d_in[1];
  const int*   ys    = (const int*)d_in[2];
  const int*   ylens = (const int*)d_in[3];
  const float* W     = (const float*)d_in[4];
  const float* bias  = (const float*)d_in[5];
  float*       out   = (float*)d_out;
  char*        ws    = (char*)d_ws;

  // workspace carve (bytes)
  const size_t off_hsb    = 0;                               // 16,777,216
  const size_t off_Wb     = off_hsb    + (size_t)Nn*Tt*IDIM*2;
  const size_t off_plab   = off_Wb     + (size_t)Vv*IDIM*2;  // 8,650,752
  const size_t off_pkP    = off_plab   + (size_t)Nn*LS*Tt*4; // 8,388,608
  const size_t off_psum   = off_pkP    + (size_t)Nn*Tt*128*4;
  const size_t off_lse    = off_psum   + (size_t)64*16384*4;
  const size_t off_labmap = off_lse    + (size_t)16384*4;
  const size_t off_extidx = off_labmap + (size_t)Nn*Vv*4;
  const size_t off_skip   = off_extidx + (size_t)((Nn*Ll*4 + 255) & ~255);

  bfu16* hsb    = (bfu16*)(ws + off_hsb);
  bfu16* Wb     = (bfu16*)(ws + off_Wb);
  float* plabT  = (float*)(ws + off_plab);
  float* pkP    = (float*)(ws + off_pkP);
  float* psum   = (float*)(ws + off_psum);
  float* lse    = (float*)(ws + off_lse);
  int*   labmap = (int*)(ws + off_labmap);
  int*   extidx = (int*)(ws + off_extidx);
  int*   skipf  = (int*)(ws + off_skip);

  convert_zero<<<2048, 256, 0, stream>>>(
      (const float4*)hs, (const float4*)W, (ushort4*)hsb, (ushort4*)Wb, out);
  build_labels<<<16, 256, 0, stream>>>(ys, labmap, extidx, skipf);
  gemm_lse<<<1024, 512, 0, stream>>>(hsb, Wb, bias, labmap, plabT, psum);
  build_pkP<<<256, 256, 0, stream>>>(plabT, extidx, pkP);
  lse_reduce<<<64, 256, 0, stream>>>(psum, lse);
  ctc_dp<<<16, 64, 0, stream>>>(plabT, pkP, lse, skipf, hlens, ylens, out);
}

// Round 24
// 172.487 us; speedup vs baseline: 1.5546x; 1.0563x over previous
//
#include <hip/hip_runtime.h>
#include <cstdint>
#include <cstddef>

// ---------- types ----------
using short8_t = __attribute__((ext_vector_type(8))) short;
using f32x4    = __attribute__((ext_vector_type(4))) float;
typedef unsigned short bfu16;

constexpr int   Nn   = 16;
constexpr int   Tt   = 1024;
constexpr int   IDIM = 512;
constexpr int   Vv   = 4096;
constexpr int   Ss   = 128;
constexpr int   Ll   = 2 * Ss + 1;   // 257
constexpr int   LS   = 132;          // slot count (pad 129 -> 132)
constexpr int   PST  = LS * Tt;      // per-sample plabT stride (floats)
constexpr float NEGV = -1e30f;
constexpr float L2E  = 1.4426950408889634f;  // log2(e)
constexpr float LN2  = 0.6931471805599453f;  // ln(2)

// ---------- helpers ----------
__device__ __forceinline__ float fexp2(float x) { return __builtin_amdgcn_exp2f(x); }
__device__ __forceinline__ float flog2(float x) { return __builtin_amdgcn_logf(x); }

// DPP wave_shr:1 lane shift (lane i <- lane i-1), lane 0 -> 0 (bound_ctrl).
__device__ __forceinline__ float dpp_shr1(float x) {
  return __int_as_float(__builtin_amdgcn_update_dpp(
      0, __float_as_int(x), 0x138, 0xf, 0xf, true));
}
__device__ __forceinline__ float dpp_shr2(float x) {   // lanes 0,1 -> 0
  return dpp_shr1(dpp_shr1(x));
}

// 16-lane rotate-reduce sum via DPP row_ror (pure VALU).
__device__ __forceinline__ float rowsum16(float s) {
  s += __int_as_float(__builtin_amdgcn_update_dpp(0, __float_as_int(s), 0x121, 0xf, 0xf, false));
  s += __int_as_float(__builtin_amdgcn_update_dpp(0, __float_as_int(s), 0x122, 0xf, 0xf, false));
  s += __int_as_float(__builtin_amdgcn_update_dpp(0, __float_as_int(s), 0x124, 0xf, 0xf, false));
  s += __int_as_float(__builtin_amdgcn_update_dpp(0, __float_as_int(s), 0x128, 0xf, 0xf, false));
  return s;
}

// 16-lane rotate-reduce max via DPP row_ror.
__device__ __forceinline__ float rowmax16(float v) {
  v = fmaxf(v, __int_as_float(__builtin_amdgcn_update_dpp(0, __float_as_int(v), 0x121, 0xf, 0xf, false)));
  v = fmaxf(v, __int_as_float(__builtin_amdgcn_update_dpp(0, __float_as_int(v), 0x122, 0xf, 0xf, false)));
  v = fmaxf(v, __int_as_float(__builtin_amdgcn_update_dpp(0, __float_as_int(v), 0x124, 0xf, 0xf, false)));
  v = fmaxf(v, __int_as_float(__builtin_amdgcn_update_dpp(0, __float_as_int(v), 0x128, 0xf, 0xf, false)));
  return v;
}

__device__ __forceinline__ bfu16 f2bf(float f) {
  unsigned int x = __float_as_uint(f);
  x = x + 0x7fffu + ((x >> 16) & 1u);   // RNE (inputs are finite normals)
  return (bfu16)(x >> 16);
}

__device__ __forceinline__ void async16(const void* g, void* l) {
  __builtin_amdgcn_global_load_lds(
      (__attribute__((address_space(1))) void*)(g),
      (__attribute__((address_space(3))) void*)(l), 16, 0, 0);
}

// ---------- kernel 1: fp32 -> bf16 convert + zero output ----------
__global__ void convert_zero(const float4* __restrict__ hs4,
                             const float4* __restrict__ W4,
                             ushort4* __restrict__ hsb4,
                             ushort4* __restrict__ Wb4,
                             float* __restrict__ out) {
  if (blockIdx.x == 0 && threadIdx.x == 0) out[0] = 0.f;
  const int HS4 = (Nn * Tt * IDIM) / 4;        // 2097152
  const int TOT = HS4 + (Vv * IDIM) / 4;       // +524288
  for (int i = blockIdx.x * 256 + threadIdx.x; i < TOT; i += gridDim.x * 256) {
    float4 f;
    if (i < HS4) f = hs4[i]; else f = W4[i - HS4];
    ushort4 o;
    o.x = f2bf(f.x); o.y = f2bf(f.y); o.z = f2bf(f.z); o.w = f2bf(f.w);
    if (i < HS4) hsb4[i] = o; else Wb4[i - HS4] = o;
  }
}

// ---------- kernel 2: build label map / extended sequence ----------
__global__ void build_labels(const int* __restrict__ ys,
                             int* __restrict__ labmap,
                             int* __restrict__ extidx,
                             int* __restrict__ skipflag) {
  const int n = blockIdx.x, tid = threadIdx.x;
  int* lm = labmap + n * Vv;
  for (int v = tid; v < Vv; v += 256) lm[v] = 0x7fffffff;
  __syncthreads();
  if (tid == 0) lm[0] = 0;                                  // blank -> slot 0
  if (tid < Ss) atomicMin(&lm[ys[n * Ss + tid]], tid + 1);  // canonical = first occurrence
  __syncthreads();
  for (int s = tid; s < Ll; s += 256) {
    int v = (s & 1) ? ys[n * Ss + ((s - 1) >> 1)] : 0;
    extidx[n * Ll + s] = lm[v];
    int allow = 0;
    if ((s & 1) && s >= 3) allow = (v != ys[n * Ss + ((s - 3) >> 1)]) ? 1 : 0;
    skipflag[n * Ll + s] = allow;
  }
  __syncthreads();
  for (int v = tid; v < Vv; v += 256)
    if (lm[v] == 0x7fffffff) lm[v] = -1;
}

// ---------- kernel 3: 256x256 BK=64 8-wave MFMA GEMM fused with lse + label scatter ----
// R21 (verified 78us): counted-vmcnt pipeline + early read-barrier + stage
// interleave between MFMA quadrants. Per tile:
//   {vmcnt(8) ; barrier ; reads Q0/Q1 + MFMA Q0,Q1 ; last reads ; lgkmcnt(0) ;
//    barrier [all waves done reading buf] ; stage(t+2) issues interleaved
//    between MFMA Q2 and Q3 (register-only section => no LDS hazard)}.
// vmcnt never drains to 0 except the last tile. DPP row_ror epilogue reduce.
__global__ __launch_bounds__(512, 2) void gemm_lse(
    const bfu16* __restrict__ A,      // [16384][512] hs bf16
    const bfu16* __restrict__ B,      // [4096][512]  W  bf16 (B^T layout)
    const float* __restrict__ bias,   // [4096]
    const int*   __restrict__ labmap, // [16][4096]
    float* __restrict__ plabT,        // [16][132][1024]  exp2(logit*L2E), transposed
    float* __restrict__ psum) {       // [64][16384]  sum of exp2(logit*L2E) partials
  __shared__ alignas(128) char ldsraw[131072];   // [buf][A/B][32KB]
  const int tid  = threadIdx.x;
  const int lane = tid & 63, wid = tid >> 6;     // 8 waves
  const int wr = wid >> 2, wc = wid & 3;         // 2M x 4N wave grid

  // bijective XCD swizzle (1024 % 8 == 0)
  const int flat = blockIdx.x;
  const int wg   = (flat & 7) * 128 + (flat >> 3);
  const int bR = wg >> 4, bC = wg & 15;
  const int rowbase = bR * 256, colbase = bC * 256;

  f32x4 acc[8][4];
#pragma unroll
  for (int m = 0; m < 8; m++)
#pragma unroll
    for (int n = 0; n < 4; n++) {
      f32x4 z = {0.f, 0.f, 0.f, 0.f};
      acc[m][n] = z;
    }

  // ---- staging setup: waves 0-3 stage A (64 rows each), 4-7 stage B ----
  const int  sw  = wid & 3;
  const bool isB = wid >= 4;
  const char* gsrc0 = (const char*)(isB ? (const void*)B : (const void*)A)
      + (size_t)((isB ? colbase : rowbase) + sw * 64 + (lane >> 3)) * (IDIM * 2)
      + (((lane & 7) ^ ((lane >> 3) & 7)) * 16);     // pre-swizzled source chunk
  char* ldst0 = ldsraw + (isB ? 32768 : 0) + sw * 8192;

  // ---- fragment-read setup ----
  const int fr = lane & 15;          // fragment row (A row / B col low bits)
  const int g  = lane >> 4;          // k-chunk 0..3 within K=32 half
  const int fx = fr & 7;             // row&7 for the XOR swizzle

  // epilogue metadata (prefetched; latency hidden under K-loop)
  const int nsamp = bR >> 2;         // 4 row-blocks (256) per sample (1024)
  const int* lm = labmap + nsamp * Vv;
  float* plT = plabT + (size_t)nsamp * PST;
  float bc[4];
  int   slot[4];
#pragma unroll
  for (int n = 0; n < 4; n++) {
    int c = colbase + wc * 64 + n * 16 + fr;
    bc[n]   = bias[c];
    slot[n] = lm[c];
  }

  auto stage = [&](int b, int t) {          // full 8-issue stage (prologue)
#pragma unroll
    for (int i = 0; i < 8; ++i)
      async16(gsrc0 + (size_t)t * 128 + i * 8192, ldst0 + b * 65536 + i * 1024);
  };
  auto stage1 = [&](int b, int t, int i) {  // single issue (interleaved)
    async16(gsrc0 + (size_t)t * 128 + (size_t)i * 8192, ldst0 + b * 65536 + i * 1024);
  };

  // prologue: tiles 0 and 1 in flight (8 loads each per wave)
  stage(0, 0);
  stage(1, 1);

  int buf = 0;
  for (int t = 0; t < 8; ++t) {
    // tile t resident; tile t+1's 8 loads may stay in flight (counted wait)
    if (t < 7) asm volatile("s_waitcnt vmcnt(8)" ::: "memory");
    else       asm volatile("s_waitcnt vmcnt(0)" ::: "memory");
    __builtin_amdgcn_s_barrier();

    const char* Ab = ldsraw + buf * 65536;
    const char* Bb = Ab + 32768;

    short8_t a0[4], a1[4], a2[4], a3[4], b0[4], b1[4];
#pragma unroll
    for (int m = 0; m < 4; m++)
      a0[m] = *(const short8_t*)(Ab + (wr * 128 + m * 16 + fr) * 128 + ((0 + g) ^ fx) * 16);
#pragma unroll
    for (int n = 0; n < 4; n++)
      b0[n] = *(const short8_t*)(Bb + (wc * 64 + n * 16 + fr) * 128 + ((0 + g) ^ fx) * 16);
#pragma unroll
    for (int m = 0; m < 4; m++)
      a1[m] = *(const short8_t*)(Ab + (wr * 128 + (m + 4) * 16 + fr) * 128 + ((0 + g) ^ fx) * 16);

    __builtin_amdgcn_s_setprio(1);
#pragma unroll
    for (int m = 0; m < 4; m++)
#pragma unroll
      for (int n = 0; n < 4; n++)
        acc[m][n] = __builtin_amdgcn_mfma_f32_16x16x32_bf16(a0[m], b0[n], acc[m][n], 0, 0, 0);
    __builtin_amdgcn_s_setprio(0);

#pragma unroll
    for (int m = 0; m < 4; m++)
      a2[m] = *(const short8_t*)(Ab + (wr * 128 + m * 16 + fr) * 128 + ((4 + g) ^ fx) * 16);
#pragma unroll
    for (int n = 0; n < 4; n++)
      b1[n] = *(const short8_t*)(Bb + (wc * 64 + n * 16 + fr) * 128 + ((4 + g) ^ fx) * 16);

    __builtin_amdgcn_s_setprio(1);
#pragma unroll
    for (int m = 0; m < 4; m++)
#pragma unroll
      for (int n = 0; n < 4; n++)
        acc[m + 4][n] = __builtin_amdgcn_mfma_f32_16x16x32_bf16(a1[m], b0[n], acc[m + 4][n], 0, 0, 0);
    __builtin_amdgcn_s_setprio(0);

#pragma unroll
    for (int m = 0; m < 4; m++)
      a3[m] = *(const short8_t*)(Ab + (wr * 128 + (m + 4) * 16 + fr) * 128 + ((4 + g) ^ fx) * 16);

    // all of this wave's ds_reads of buf are now issued; drain and sync so
    // the stage issues below may overwrite buf safely.
    asm volatile("s_waitcnt lgkmcnt(0)" ::: "memory");
    __builtin_amdgcn_s_barrier();

    const bool dostage = (t + 2 < 8);
    if (dostage) {
      stage1(buf, t + 2, 0); stage1(buf, t + 2, 1);
      stage1(buf, t + 2, 2); stage1(buf, t + 2, 3);
    }

    __builtin_amdgcn_s_setprio(1);
#pragma unroll
    for (int m = 0; m < 4; m++)
#pragma unroll
      for (int n = 0; n < 4; n++)
        acc[m][n] = __builtin_amdgcn_mfma_f32_16x16x32_bf16(a2[m], b1[n], acc[m][n], 0, 0, 0);
    __builtin_amdgcn_s_setprio(0);

    if (dostage) {
      stage1(buf, t + 2, 4); stage1(buf, t + 2, 5);
      stage1(buf, t + 2, 6); stage1(buf, t + 2, 7);
    }

    __builtin_amdgcn_s_setprio(1);
#pragma unroll
    for (int m = 0; m < 4; m++)
#pragma unroll
      for (int n = 0; n < 4; n++)
        acc[m + 4][n] = __builtin_amdgcn_mfma_f32_16x16x32_bf16(a3[m], b1[n], acc[m + 4][n], 0, 0, 0);
    __builtin_amdgcn_s_setprio(0);

    buf ^= 1;
  }

  // ---- epilogue: bias, TRANSPOSED label scatter (exp2'd), DPP-reduced sums ----
  const int g4 = g * 4;
#pragma unroll
  for (int m = 0; m < 8; m++) {
#pragma unroll
    for (int r = 0; r < 4; r++) {
      int row = rowbase + wr * 128 + m * 16 + g4 + r;
      int tIn = row & 1023;                 // t within sample
      float e0 = fexp2((acc[m][0][r] + bc[0]) * L2E);
      float e1 = fexp2((acc[m][1][r] + bc[1]) * L2E);
      float e2 = fexp2((acc[m][2][r] + bc[2]) * L2E);
      float e3 = fexp2((acc[m][3][r] + bc[3]) * L2E);
      if (slot[0] >= 0) plT[(size_t)slot[0] * Tt + tIn] = e0;
      if (slot[1] >= 0) plT[(size_t)slot[1] * Tt + tIn] = e1;
      if (slot[2] >= 0) plT[(size_t)slot[2] * Tt + tIn] = e2;
      if (slot[3] >= 0) plT[(size_t)slot[3] * Tt + tIn] = e3;
      float s = rowsum16((e0 + e1) + (e2 + e3));   // DPP row_ror reduce
      if (fr == 0) {
        int pc = bC * 4 + wc;             // 0..63
        psum[(size_t)pc * 16384 + row] = s;
      }
    }
  }
}

// ---------- kernel 4: reduce 64 sumexp2 partials per row -> lse (natural log) ----------
__global__ void lse_reduce(const float* __restrict__ psum,
                           float* __restrict__ lse) {
  int row = blockIdx.x * 256 + threadIdx.x;
  float s = 0.f;
#pragma unroll 8
  for (int j = 0; j < 64; j++)
    s += psum[(size_t)j * 16384 + row];
  lse[row] = flog2(s) * LN2;
}

// ---------- kernel 5: CTC forward DP, one wave per sample ----------
// LINEAR-domain, QUAD-step-batched (R15 algebra) on TRANSPOSED probabilities
// (R16 streaming loads) with DPP wave_shr lane shifts (R17). R21: rescale
// max-reduce uses DPP row_ror for offsets 1..8 (only 2 ds_bpermute remain).
__global__ __launch_bounds__(64) void ctc_dp(
    const float* __restrict__ plabT, const float* __restrict__ lse,
    const int* __restrict__ extidx, const int* __restrict__ skipflag,
    const int* __restrict__ hlens, const int* __restrict__ ylens,
    float* __restrict__ out) {
  __shared__ float alf[264];
  const int n    = blockIdx.x;
  const int lane = threadIdx.x;
  const int hlen = hlens[n];
  const int Ln   = 2 * ylens[n] + 1;
  const int sbase = lane * 4;   // states sbase..sbase+3; lane 63 also owns s=256

  const int   e1  = extidx[n * Ll + sbase + 1];
  const int   e3  = extidx[n * Ll + sbase + 3];
  const float sk1 = skipflag[n * Ll + sbase + 1] ? 1.f : 0.f;
  const float sk3 = skipflag[n * Ll + sbase + 3] ? 1.f : 0.f;
  const float skh = (lane > 0 && skipflag[n * Ll + sbase - 1]) ? 1.f : 0.f;  // state s-1
  const float skz = (lane > 0 && skipflag[n * Ll + sbase - 3]) ? 1.f : 0.f;  // state s-3
  const float skv = (lane > 1 && skipflag[n * Ll + sbase - 5]) ? 1.f : 0.f;  // state s-5
  const bool  l0  = (lane == 0);
  // validity masks (applied only at rescale)
  const float m0  = (sbase + 0 < Ln) ? 1.f : 0.f;
  const float m1  = (sbase + 1 < Ln) ? 1.f : 0.f;
  const float m2  = (sbase + 2 < Ln) ? 1.f : 0.f;
  const float m3  = (sbase + 3 < Ln) ? 1.f : 0.f;
  const float m4  = (lane == 63 && Ln == 257) ? 1.f : 0.f;

  const float* pl  = plabT + (size_t)n * PST;
  const float* rb  = pl;                          // blank row (slot 0), uniform
  const float* r1p = pl + (size_t)e1 * Tt;        // per-lane e1 stream
  const float* r3p = pl + (size_t)e3 * Tt;        // per-lane e3 stream
  const float* lsp = lse + n * Tt;

  // sum of lse over t < hlen (16 independent loads, one latency exposure)
  float slse = 0.f;
#pragma unroll
  for (int j = 0; j < 16; j++) {
    int t = lane + 64 * j;
    float v = lsp[t];
    slse += (t < hlen) ? v : 0.f;
  }
#pragma unroll
  for (int off = 32; off; off >>= 1) slse += __shfl_xor(slse, off);

  // t = 0 init: alpha[0] = p_blank(0), alpha[1] = p_y1(0)
  float a0 = 0.f, a1 = 0.f, a2 = 0.f, a3 = 0.f, a4 = 0.f;
  if (l0) { a0 = rb[0]; a1 = r1p[0]; }

  int sc = 0;   // accumulated log2 scale (true alpha = stored * 2^sc)

  // ---- verified single/pair paths (startup + tail), DPP shifts ----
  auto step1 = [&](float pb, float p1, float p3) {
    float pm1 = dpp_shr1(a3);          // alpha[sbase-1], lane0 -> 0
    float n4 = (a4 + a3) * pb;
    float n3 = (a3 + a2 + sk3 * a1) * p3;
    float n2 = (a2 + a1) * pb;
    float n1 = (a1 + a0 + sk1 * pm1) * p1;
    float n0 = (a0 + pm1) * pb;
    a0 = n0; a1 = n1; a2 = n2; a3 = n3; a4 = n4;
  };

  auto pair2 = [&](float pbA, float p1A, float p3A,
                   float pbB, float p1B, float p3B) {
    float pa3 = dpp_shr1(a3);
    float pa2 = dpp_shr1(a2);
    float pa1 = dpp_shr1(a1);
    float prA = dpp_shr1(p3A);         // lane0 value irrelevant (h1 factor 0)
    float h1 = (pa3 + pa2 + skh * pa1) * prA;
    float s4 = (a4 + a3) * pbA;
    float s3 = (a3 + a2 + sk3 * a1) * p3A;
    float s2 = (a2 + a1) * pbA;
    float s1 = (a1 + a0 + sk1 * pa3) * p1A;
    float s0 = (a0 + pa3) * pbA;
    a4 = (s4 + s3) * pbB;
    a3 = (s3 + s2 + sk3 * s1) * p3B;
    a2 = (s2 + s1) * pbB;
    a1 = (s1 + s0 + sk1 * h1) * p1B;
    a0 = (s0 + h1) * pbB;
  };

  auto rescale = [&]() {
    a0 *= m0; a1 *= m1; a2 *= m2; a3 *= m3; a4 *= m4;   // mask garbage (R9 fix)
    float mx = fmaxf(fmaxf(a0, a1), fmaxf(a2, a3));
    mx = fmaxf(mx, a4);
    mx = rowmax16(mx);                        // DPP within 16-lane rows
    mx = fmaxf(mx, __shfl_xor(mx, 16));       // cross-row
    mx = fmaxf(mx, __shfl_xor(mx, 32));       // cross-half
    int ee = (int)((__float_as_uint(mx) >> 23) & 0xff) - 127;
    ee = (mx > 0.f) ? ee : 0;
    float s = __uint_as_float((unsigned)(127 - ee) << 23);
    sc += ee;
    a0 *= s; a1 *= s; a2 *= s; a3 *= s; a4 *= s;
  };

  // ---- superblock (16 steps) register ring, double-buffered ----
  float pb_[2][4][4], p1_[2][4][4], p3_[2][4][4];
  float hx_[2][4][3], hz_[2][4][2], hv_[2][4];

  auto loadSB = [&](int sl, int t4) {
#pragma unroll
    for (int q = 0; q < 4; q++) {
      float4 vb = *(const float4*)(rb  + t4 + 4 * q);
      float4 v1 = *(const float4*)(r1p + t4 + 4 * q);
      float4 v3 = *(const float4*)(r3p + t4 + 4 * q);
      pb_[sl][q][0] = vb.x; pb_[sl][q][1] = vb.y; pb_[sl][q][2] = vb.z; pb_[sl][q][3] = vb.w;
      p1_[sl][q][0] = v1.x; p1_[sl][q][1] = v1.y; p1_[sl][q][2] = v1.z; p1_[sl][q][3] = v1.w;
      p3_[sl][q][0] = v3.x; p3_[sl][q][1] = v3.y; p3_[sl][q][2] = v3.z; p3_[sl][q][3] = v3.w;
    }
  };

  auto haloSB = [&](int sl) {
#pragma unroll
    for (int q = 0; q < 4; q++) {
      hx_[sl][q][0] = dpp_shr1(p3_[sl][q][0]);
      hx_[sl][q][1] = dpp_shr1(p3_[sl][q][1]);
      hx_[sl][q][2] = dpp_shr1(p3_[sl][q][2]);
      hz_[sl][q][0] = dpp_shr1(p1_[sl][q][0]);
      hz_[sl][q][1] = dpp_shr1(p1_[sl][q][1]);
      hv_[sl][q]    = dpp_shr2(p3_[sl][q][0]);
    }
  };

  auto quadsSB = [&](int sl) {
#pragma unroll
    for (int q = 0; q < 4; q++) {
      float x0 = dpp_shr1(a3);   // alpha_t[s-1], lane0 -> 0
      float y0 = dpp_shr1(a2);   // alpha_t[s-2]
      float z0 = dpp_shr1(a1);   // alpha_t[s-3]
      float w0 = dpp_shr1(a0);   // alpha_t[s-4]
      float v0 = dpp_shr2(a3);   // alpha_t[s-5], lanes 0,1 -> 0
      float u0 = dpp_shr2(a2);   // alpha_t[s-6]
      float q0 = dpp_shr2(a1);   // alpha_t[s-7]

      float v1 = (v0 + u0 + skv * q0) * hv_[sl][q];
      float w1 = (w0 + v0) * pb_[sl][q][0];
      float z1 = (z0 + w0 + skz * v0) * hz_[sl][q][0];
      float y1 = (y0 + z0) * pb_[sl][q][0];
      float x1 = (x0 + y0 + skh * z0) * hx_[sl][q][0];
      float z2 = (z1 + w1 + skz * v1) * hz_[sl][q][1];
      float y2 = (y1 + z1) * pb_[sl][q][1];
      float x2 = (x1 + y1 + skh * z1) * hx_[sl][q][1];
      float x3 = (x2 + y2 + skh * z2) * hx_[sl][q][2];

      float xk[4] = {x0, x1, x2, x3};
#pragma unroll
      for (int r = 0; r < 4; r++) {
        float pb = pb_[sl][q][r], p1v = p1_[sl][q][r], p3v = p3_[sl][q][r];
        float n4 = (a4 + a3) * pb;
        float n3 = (a3 + a2 + sk3 * a1) * p3v;
        float n2 = (a2 + a1) * pb;
        float n1 = (a1 + a0 + sk1 * xk[r]) * p1v;
        float n0 = (a0 + xk[r]) * pb;
        a0 = n0; a1 = n1; a2 = n2; a3 = n3; a4 = n4;
      }
    }
  };

  const int nsteps = hlen - 1;        // steps consume rows 1..hlen-1

  // startup singles t=1..3 (align superblocks to t%4==0)
  int t = 1;
  while (t < 4 && t <= nsteps) {
    step1(rb[t], r1p[t], r3p[t]);
    ++t;
  }

  const int nSB = (nsteps >= 19) ? (nsteps - 3) / 16 : 0;   // superblocks from t=4
  int t4 = 4;
  if (nSB > 0) loadSB(0, t4);

  int done = 0;
  while (done + 2 <= nSB) {
    if (done + 1 < nSB) loadSB(1, t4 + 16);
    haloSB(0); quadsSB(0);
    if (done + 2 < nSB) loadSB(0, t4 + 32);
    haloSB(1); quadsSB(1);
    rescale();                        // every 32 steps
    done += 2; t4 += 32;
  }
  if (done < nSB) {                   // odd leftover superblock (data in slot 0)
    haloSB(0); quadsSB(0);
    rescale();
    t4 += 16;
  }
  t = 4 + 16 * nSB;

  // tail: pairs then single (direct transposed scalar loads)
  for (; t + 1 <= nsteps; t += 2) {
    pair2(rb[t], r1p[t], r3p[t], rb[t + 1], r1p[t + 1], r3p[t + 1]);
  }
  if (t <= nsteps) {
    step1(rb[t], r1p[t], r3p[t]);
  }
  rescale();                          // final mask + normalize before readout

  alf[sbase + 0] = a0; alf[sbase + 1] = a1;
  alf[sbase + 2] = a2; alf[sbase + 3] = a3;
  if (lane == 63) alf[256] = a4;
  __syncthreads();
  if (l0) {
    float sum = alf[Ln - 1] + alf[Ln - 2];
    float per = 0.f;
    if (sum > 0.f) {
      float llv = (flog2(sum) + (float)sc) * LN2 - slse;
      if (llv > -1e29f) per = -llv;
    }
    atomicAdd(out, per * (1.0f / 16.0f));
  }
}

// ---------- launcher ----------
extern "C" void kernel_launch(void* const* d_in, const int* in_sizes, int n_in,
                              void* d_out, int out_size, void* d_ws, size_t ws_size,
                              hipStream_t stream) {
  const float* hs    = (const float*)d_in[0];
  const int*   hlens = (const int*)d_in[1];
  const int*   ys    = (const int*)d_in[2];
  const int*   ylens = (const int*)d_in[3];
  const float* W     = (const float*)d_in[4];
  const float* bias  = (const float*)d_in[5];
  float*       out   = (float*)d_out;
  char*        ws    = (char*)d_ws;

  // workspace carve (bytes)
  const size_t off_hsb    = 0;                               // 16,777,216
  const size_t off_Wb     = off_hsb    + (size_t)Nn*Tt*IDIM*2;
  const size_t off_plab   = off_Wb     + (size_t)Vv*IDIM*2;  // 8,650,752 (transposed)
  const size_t off_psum   = off_plab   + (size_t)Nn*LS*Tt*4;
  const size_t off_lse    = off_psum   + (size_t)64*16384*4;
  const size_t off_labmap = off_lse    + (size_t)16384*4;
  const size_t off_extidx = off_labmap + (size_t)Nn*Vv*4;
  const size_t off_skip   = off_extidx + (size_t)((Nn*Ll*4 + 255) & ~255);

  bfu16* hsb    = (bfu16*)(ws + off_hsb);
  bfu16* Wb     = (bfu16*)(ws + off_Wb);
  float* plabT  = (float*)(ws + off_plab);
  float* psum   = (float*)(ws + off_psum);
  float* lse    = (float*)(ws + off_lse);
  int*   labmap = (int*)(ws + off_labmap);
  int*   extidx = (int*)(ws + off_extidx);
  int*   skipf  = (int*)(ws + off_skip);

  convert_zero<<<2048, 256, 0, stream>>>(
      (const float4*)hs, (const float4*)W, (ushort4*)hsb, (ushort4*)Wb, out);
  build_labels<<<16, 256, 0, stream>>>(ys, labmap, extidx, skipf);
  gemm_lse<<<1024, 512, 0, stream>>>(hsb, Wb, bias, labmap, plabT, psum);
  lse_reduce<<<64, 256, 0, stream>>>(psum, lse);
  ctc_dp<<<16, 64, 0, stream>>>(plabT, lse, extidx, skipf, hlens, ylens, out);
}